// Round 4
// baseline (368.970 us; speedup 1.0000x reference)
//
#include <hip/hip_runtime.h>
#include <math.h>

#define NBINS 15
#define NCLS 100
#define ECE_EPS 1e-5f

#define TPB 128                        // 2 waves per block
#define ROWS 128                       // rows per tile
#define TILE_BYTES (ROWS * 400)        // 51200 B of logits per tile
#define SLOTS (TILE_BYTES / 16)        // 3200 16-byte slots
#define SPT (SLOTS / TPB)              // 25 float4 loads per thread
#define LDS_STRIDE 512                 // padded LDS row stride (32 slots)
#define NREP 16                        // histogram replicas
#define GRID 512                       // 2 blocks/CU x 256 CU; 4096/512 = 8 tiles/block exact

// Kernel A: argmax histogram via register-staged coalesced loads (NO global_load_lds).
//
// predictions = max(log_softmax) < 0 strictly for these inputs while labels >= 0,
// so accuracies == 0 identically; exp/log pass and labels read are dropped.
// argmax(logits) == argmax(log_softmax) exactly (per-row monotone shift).
// Output depends only on the integer argmax histogram -> bit-identical result.
//
// Round-3 lesson: two structurally different global_load_lds pipelines both pinned
// at ~115 us (~1.8 TB/s). Suspect: compiler cannot prove DMA-dest / ds_read
// disjointness -> conservative vmcnt(0) serializes every tile at full latency.
// This version stages via registers: 25 independent global_load_dwordx4 per lane
// (coalesced: slot s = i*128+tid -> each wave instr reads a contiguous 1 KiB),
// then scatters to LDS with per-lane computed (paddable, swizzlable) addresses,
// then each thread scans its own row. Compiler inserts progressive vmcnt(N)
// before each ds_write -> transfer of 51.2 KB streams with deep ILP.
//
// LDS layout: row r at r*512B; 16B slot j stored at slot (j ^ (r&7)).
//  - b128 scan reads: bank start = 4*((i&7)^(t&7)) with 128t = 0 mod 32 ->
//    8 distinct 4-bank groups x 8 lanes = minimum cycles, conflict-free.
//  - b128 scatter writes: starts 4*((j&7)^(r&7)) ~uniform -> ~minimum.
__global__ __launch_bounds__(TPB) void ece_hist(const float4* __restrict__ lg4,
                                                int* __restrict__ g_cnt,   // [NREP][NCLS]
                                                int n_rows, int n_tiles) {
    __shared__ __align__(16) char tile[ROWS * LDS_STRIDE];   // 64 KB
    __shared__ int s_cnt[NCLS];

    const int tid = threadIdx.x;
    if (tid < NCLS) s_cnt[tid] = 0;
    __syncthreads();

    for (int t = blockIdx.x; t < n_tiles; t += gridDim.x) {
        const float4* __restrict__ src = lg4 + (long)t * (TILE_BYTES / 16);

        // ---- 25 independent coalesced loads into registers (static indexing) ----
        float4 v[SPT];
        #pragma unroll
        for (int i = 0; i < SPT; ++i) v[i] = src[i * TPB + tid];

        // ---- scatter to padded+swizzled LDS: slot s = i*128+tid -> (r = s/25, j = s%25)
        // incremental: s += 128 == (r += 5, j += 3, carry)  [128 = 5*25 + 3]
        int r = tid / 25;
        int j = tid % 25;
        #pragma unroll
        for (int i = 0; i < SPT; ++i) {
            *(float4*)(&tile[r * LDS_STRIDE + 16 * (j ^ (r & 7))]) = v[i];
            j += 3; r += 5;
            if (j >= 25) { j -= 25; r += 1; }
        }
        __syncthreads();

        // ---- thread t scans row t (100 floats, first-occurrence argmax) ----
        float m = -INFINITY; int mi = 0;
        const char* rowb = &tile[tid * LDS_STRIDE];
        const int sw = tid & 7;
        #pragma unroll
        for (int i = 0; i < 25; ++i) {
            const float4 f = *(const float4*)(rowb + 16 * (i ^ sw));
            const int c = 4 * i;
            if (f.x > m) { m = f.x; mi = c;     }
            if (f.y > m) { m = f.y; mi = c + 1; }
            if (f.z > m) { m = f.z; mi = c + 2; }
            if (f.w > m) { m = f.w; mi = c + 3; }
        }
        atomicAdd(&s_cnt[mi], 1);
        __syncthreads();   // scan done before next tile's LDS writes
    }

    // ---- tail rows (n_rows % 128); zero iterations at N=524288 ----
    for (int row = n_tiles * ROWS + blockIdx.x * blockDim.x + tid;
         row < n_rows; row += gridDim.x * blockDim.x) {
        const float* p = (const float*)lg4 + (long)row * NCLS;
        float m = -INFINITY; int mi = 0;
        for (int c = 0; c < NCLS; ++c) { const float fv = p[c]; if (fv > m) { m = fv; mi = c; } }
        atomicAdd(&s_cnt[mi], 1);
    }
    __syncthreads();

    // ---- one flush per block to a histogram replica ----
    int* rep = g_cnt + (blockIdx.x & (NREP - 1)) * NCLS;
    if (tid < NCLS) {
        const int c = s_cnt[tid];
        if (c) atomicAdd(&rep[tid], c);
    }
}

// Kernel B: fold the 100-entry histogram into the 15-bin sums and the final scalar.
// coeff(c,b) = softmax_b( -(c - anchor_b)^2 / 0.01 ), identical math to reference.
__global__ void ece_final(const int* __restrict__ g_cnt,      // [NREP][NCLS]
                          const float* __restrict__ g_acc,    // [NCLS], stays 0
                          float* __restrict__ out) {
    __shared__ float s_bins[3 * NBINS];
    const int tid = threadIdx.x;
    if (tid < 3 * NBINS) s_bins[tid] = 0.0f;
    __syncthreads();

    if (tid < NCLS) {
        int ci = 0;
        #pragma unroll
        for (int rp = 0; rp < NREP; ++rp) ci += g_cnt[rp * NCLS + tid];
        const float cnt  = (float)ci;
        const float accv = g_acc[tid];        // identically 0, kept faithful
        const float conf = (float)tid;

        float diff[NBINS];
        float dm = -INFINITY;
        #pragma unroll
        for (int b = 0; b < NBINS; ++b) {
            const float a = (float)(2 * b + 1) * (1.0f / 30.0f);
            const float d = conf - a;
            diff[b] = -(d * d) * 100.0f;
            dm = fmaxf(dm, diff[b]);
        }
        float es = 0.0f;
        float e[NBINS];
        #pragma unroll
        for (int b = 0; b < NBINS; ++b) { e[b] = __expf(diff[b] - dm); es += e[b]; }
        const float inv = 1.0f / es;
        #pragma unroll
        for (int b = 0; b < NBINS; ++b) {
            const float coeff = e[b] * inv;
            atomicAdd(&s_bins[b],             cnt * coeff);
            atomicAdd(&s_bins[NBINS + b],     conf * cnt * coeff);
            atomicAdd(&s_bins[2 * NBINS + b], accv * coeff);
        }
    }
    __syncthreads();

    if (tid == 0) {
        float total = 0.0f;
        #pragma unroll
        for (int b = 0; b < NBINS; ++b) total += fabsf(s_bins[b]);
        const float invw = 1.0f / fmaxf(total, ECE_EPS);
        float ece = 0.0f;
        #pragma unroll
        for (int b = 0; b < NBINS; ++b) {
            const float sc = s_bins[b];
            const float denom = fmaxf(sc, ECE_EPS);
            const float bc = s_bins[NBINS + b] / denom;
            const float ba = s_bins[2 * NBINS + b] / denom;
            const float d  = bc - ba;
            ece += d * d * (sc * invw);
        }
        out[0] = sqrtf(ece);
    }
}

extern "C" void kernel_launch(void* const* d_in, const int* in_sizes, int n_in,
                              void* d_out, int out_size, void* d_ws, size_t ws_size,
                              hipStream_t stream) {
    const float4* lg4 = (const float4*)d_in[0];
    const int n_rows = in_sizes[1];   // labels element count = N

    // workspace: g_cnt[16][100] ints | g_acc[100] floats
    int*   g_cnt = (int*)d_ws;
    float* g_acc = (float*)((char*)d_ws + NREP * NCLS * sizeof(int));
    float* outp  = (float*)d_out;

    const int n_tiles = n_rows / ROWS;           // 4096
    int grid = (n_tiles < GRID) ? n_tiles : GRID;
    if (grid < 1) grid = 1;

    hipMemsetAsync(d_ws, 0, NREP * NCLS * sizeof(int) + NCLS * sizeof(float), stream);
    // 64.4 KB LDS/block -> 2 blocks/CU; 8 tiles/block exactly at N=524288.
    ece_hist<<<grid, TPB, 0, stream>>>(lg4, g_cnt, n_rows, n_tiles);
    ece_final<<<1, 128, 0, stream>>>(g_cnt, g_acc, outp);
}